// Round 2
// baseline (355.800 us; speedup 1.0000x reference)
//
#include <hip/hip_runtime.h>
#include <hip/hip_bf16.h>

// Problem: S=2048, B=32, H=1024
//   energies[s,b] = dot(hidden[b,:], enc[s,b,:])   (enc is [S,B,H] row-major)
//   out[b,0,s]    = softmax_over_s(energies)[s,b]
// HBM-bound: enc = 256 MB read once -> ~40 us floor at 6.3-6.7 TB/s.
// Measured dur_us includes ~300 us of harness reset traffic (1 GB ws poison +
// 256 MB input restore) -- controllable slice is the ~50 us on top.

#define SEQ_LEN 2048
#define BATCH   32
#define HIDDEN  1024
#define ROWS_PER_WAVE 8
#define NWAVES (SEQ_LEN * BATCH / ROWS_PER_WAVE)   // 8192 waves
#define NBLOCKS (NWAVES / 4)                       // 2048 blocks of 256

// Each wave owns 8 rows, all with the same b (row stride 8192 = 0 mod 32):
//   rows w + 8192*r, r=0..7. hidden[b] lives in 16 VGPRs, loaded once.
// 8 independent accumulators -> up to 32 outstanding enc loads per wave.
__global__ __launch_bounds__(256) void dot_kernel(
    const float* __restrict__ hidden,
    const float* __restrict__ enc,
    float* __restrict__ energies /* [B, S] */) {

    const int gtid = blockIdx.x * blockDim.x + threadIdx.x;
    const int w    = gtid >> 6;           // wave id, 0..8191
    const int lane = threadIdx.x & 63;

    const int b  = w & (BATCH - 1);       // same b for all 8 rows
    const int s0 = w >> 5;                // first row's s; subsequent += 256

    // hidden[b] once: lane reads float4 at lane + 64k, k=0..3
    const float4* __restrict__ hid4 = (const float4*)(hidden + (size_t)b * HIDDEN);
    float4 h[4];
#pragma unroll
    for (int k = 0; k < 4; ++k) h[k] = hid4[lane + 64 * k];

    float acc[ROWS_PER_WAVE];
#pragma unroll
    for (int r = 0; r < ROWS_PER_WAVE; ++r) acc[r] = 0.0f;

#pragma unroll
    for (int r = 0; r < ROWS_PER_WAVE; ++r) {
        const size_t row = (size_t)(w + NWAVES * r);
        const float4* __restrict__ row4 = (const float4*)(enc + row * HIDDEN);
#pragma unroll
        for (int k = 0; k < 4; ++k) {
            float4 a = row4[lane + 64 * k];
            acc[r] += a.x * h[k].x + a.y * h[k].y + a.z * h[k].z + a.w * h[k].w;
        }
    }

    // 8 independent 64-lane butterfly reductions (ILP hides shuffle latency)
#pragma unroll
    for (int off = 32; off > 0; off >>= 1) {
#pragma unroll
        for (int r = 0; r < ROWS_PER_WAVE; ++r)
            acc[r] += __shfl_xor(acc[r], off, 64);
    }

    if (lane == 0) {
#pragma unroll
        for (int r = 0; r < ROWS_PER_WAVE; ++r) {
            const int s = s0 + (NWAVES / BATCH) * r;   // +256 per r
            energies[b * SEQ_LEN + s] = acc[r];
        }
    }
}

// One block per batch column: softmax over S=2048. 256 threads x 8 values,
// register-resident; two block reductions (max, sum) through LDS.
__global__ __launch_bounds__(256) void softmax_kernel(
    const float* __restrict__ energies /* [B, S] */,
    float* __restrict__ out /* [B, 1, S] */) {

    const int b   = blockIdx.x;
    const int tid = threadIdx.x;
    const float* __restrict__ e = energies + (size_t)b * SEQ_LEN;
    float* __restrict__ o       = out      + (size_t)b * SEQ_LEN;

    float v[8];
    float m = -1e30f;
#pragma unroll
    for (int i = 0; i < 8; ++i) {
        v[i] = e[tid + i * 256];
        m = fmaxf(m, v[i]);
    }

    const int wave = tid >> 6, lane = tid & 63;
    __shared__ float smax[4];
    __shared__ float ssum[4];

#pragma unroll
    for (int off = 32; off > 0; off >>= 1)
        m = fmaxf(m, __shfl_xor(m, off, 64));
    if (lane == 0) smax[wave] = m;
    __syncthreads();
    const float bm = fmaxf(fmaxf(smax[0], smax[1]), fmaxf(smax[2], smax[3]));

    float sum = 0.0f;
#pragma unroll
    for (int i = 0; i < 8; ++i) {
        v[i] = __expf(v[i] - bm);
        sum += v[i];
    }
#pragma unroll
    for (int off = 32; off > 0; off >>= 1)
        sum += __shfl_xor(sum, off, 64);
    if (lane == 0) ssum[wave] = sum;
    __syncthreads();
    const float inv = 1.0f / (ssum[0] + ssum[1] + ssum[2] + ssum[3]);

#pragma unroll
    for (int i = 0; i < 8; ++i)
        o[tid + i * 256] = v[i] * inv;
}

extern "C" void kernel_launch(void* const* d_in, const int* in_sizes, int n_in,
                              void* d_out, int out_size, void* d_ws, size_t ws_size,
                              hipStream_t stream) {
    const float* hidden = (const float*)d_in[0];   // [B, H]
    const float* enc    = (const float*)d_in[1];   // [S, B, H]
    float* out          = (float*)d_out;           // [B, 1, S]
    float* energies     = (float*)d_ws;            // [B, S] = 256 KB scratch

    dot_kernel<<<NBLOCKS, 256, 0, stream>>>(hidden, enc, energies);
    softmax_kernel<<<BATCH, 256, 0, stream>>>(energies, out);
}